// Round 9
// baseline (2069.552 us; speedup 1.0000x reference)
//
#include <hip/hip_runtime.h>
#include <stdint.h>

#define HTABLE (1u << 19)
#define TMASK  (HTABLE - 1u)
#define TILE   64
#define KSTR   264   // hB row stride in bf16 elems (528 B)
#define KE     40    // encB row stride in bf16 elems

#define NTILE   8196               // 64-pt mlp tiles (= NCHUNK*4)
#define NCHUNK  2049               // 256-pt chunks of the permuted stream (INCLUDES overflow chunk)
#define BPAD    (NCHUNK * 256)     // padded point count 524544

// fused prep-kernel block ranges
#define PACK_N  32768              // 16*2^19/256
#define PREP_N  196
#define COUNT_N 2048               // B/256
#define PERM_N  2049               // BPAD/256 perm-init blocks

typedef __attribute__((ext_vector_type(8))) short short8;
typedef __attribute__((ext_vector_type(4))) float floatx4;

__device__ __forceinline__ float relu_(float v) { return fmaxf(v, 0.f); }

__device__ __forceinline__ uint32_t f2bf(float f) {
    uint32_t u = __float_as_uint(f);
    return (u + 0x7FFFu + ((u >> 16) & 1u)) >> 16;
}

// variable-index extract from a 16B quad: 3 cndmasks, no scratch
__device__ __forceinline__ uint32_t sel4(const uint4& v, uint32_t i) {
    uint32_t lo = (i & 1u) ? v.y : v.x;
    uint32_t hi = (i & 1u) ? v.w : v.z;
    return (i & 2u) ? hi : lo;
}

__device__ __constant__ uint32_t PRS[6] = {1u, 2654435761u, 805459861u, 3674653429u, 2097192037u, 1434869437u};
__device__ __constant__ float RESF[16]  = {16.f,20.f,25.f,32.f,40.f,50.f,64.f,80.f,101.f,128.f,161.f,203.f,256.f,322.f,406.f,512.f};
__device__ __constant__ float GRIDF[16] = {1.f/16.f,1.f/20.f,1.f/25.f,1.f/32.f,1.f/40.f,1.f/50.f,1.f/64.f,1.f/80.f,
                                           1.f/101.f,1.f/128.f,1.f/161.f,1.f/203.f,1.f/256.f,1.f/322.f,1.f/406.f,1.f/512.f};

// ---------------- fused prep: packtab | weight-prep | class-count | perm-init ----------------
// All four are mutually independent; one dispatch saves 3 launch overheads.
__global__ __launch_bounds__(256) void k_fusedprep(
    const float* __restrict__ emb, uint32_t* __restrict__ T,
    const float* __restrict__ Wres, const float* __restrict__ W0,
    uint16_t* __restrict__ Wrt, uint16_t* __restrict__ W0t,
    const int* __restrict__ lid, int n, int* __restrict__ cnt,
    int* __restrict__ perm)
{
    const int t = threadIdx.x;
    const int bid = blockIdx.x;
    if (bid < PACK_N) {
        const int i = bid * 256 + t;
        float2 e = ((const float2*)emb)[i];
        T[i] = f2bf(e.x) | (f2bf(e.y) << 16);
        return;
    }
    if (bid < PACK_N + PREP_N) {
        __shared__ float sm[64 * 65 > 32 * 257 ? 64 * 65 : 32 * 257];
        const int pb = bid - PACK_N;
        if (pb < 192) {
            const int c = pb / 48, rem = pb % 48, ib = rem / 16, tile = rem % 16;
            const int n0 = (tile / 4) * 64, k0 = (tile % 4) * 64;
            const float* src = Wres + (size_t)(c * 3 + ib) * 65536;
            for (int i = 0; i < 16; i++) {
                int idx = t + 256 * i, r = idx >> 6, cc = idx & 63;
                sm[r * 65 + cc] = src[(size_t)(k0 + r) * 256 + n0 + cc];
            }
            __syncthreads();
            uint16_t* dst = Wrt + (size_t)(c * 3 + ib) * 65536;
            for (int i = 0; i < 16; i++) {
                int idx = t + 256 * i, rn = idx >> 6, ck = idx & 63;
                dst[(size_t)(n0 + rn) * 256 + k0 + ck] = (uint16_t)f2bf(sm[ck * 65 + rn]);
            }
        } else {
            const int c = pb - 192;
            for (int i = 0; i < 32; i++) {
                int idx = t + 256 * i, k = idx >> 8, nn = idx & 255;
                sm[k * 257 + nn] = W0[(size_t)c * 8192 + idx];
            }
            __syncthreads();
            for (int i = 0; i < 32; i++) {
                int idx = t + 256 * i, nn = idx >> 5, k = idx & 31;
                W0t[(size_t)c * 8192 + idx] = (uint16_t)f2bf(sm[k * 257 + nn]);
            }
        }
        return;
    }
    if (bid < PACK_N + PREP_N + COUNT_N) {
        __shared__ int h4[4];
        const int i = (bid - PACK_N - PREP_N) * 256 + t;
        if (t < 4) h4[t] = 0;
        __syncthreads();
        if (i < n) atomicAdd(&h4[lid[i] & 3], 1);
        __syncthreads();
        if (t < 4) atomicAdd(&cnt[t], h4[t]);
        return;
    }
    // perm init to -1
    const int i = (bid - PACK_N - PREP_N - COUNT_N) * 256 + t;
    if (i < NTILE * TILE) perm[i] = -1;
}

__global__ void k_offsets(const int* __restrict__ cnt, int* __restrict__ cursor) {
    if (threadIdx.x == 0 && blockIdx.x == 0) {
        int off = 0;
        for (int k = 0; k < 4; k++) {
            cursor[k] = off;
            off = (off + cnt[k] + 63) & ~63;
        }
    }
}

// scatter: class-sorted perm AND the permuted coordinate stream xp[j] = x[perm[j]]
__global__ void k_scatter(const int* __restrict__ lid, const float* __restrict__ x, int n,
                          int* __restrict__ cursor, int* __restrict__ perm, float* __restrict__ xp) {
    int i = blockIdx.x * blockDim.x + threadIdx.x;
    if (i >= n) return;
    int lane = threadIdx.x & 63;
    int c = lid[i] & 3;
    unsigned long long m0 = __ballot(c == 0), m1 = __ballot(c == 1);
    unsigned long long m2 = __ballot(c == 2), m3 = __ballot(c == 3);
    unsigned long long mc = (c == 0) ? m0 : (c == 1) ? m1 : (c == 2) ? m2 : m3;
    int rank = __popcll(mc & ((1ull << lane) - 1ull));
    int cntl = (lane == 0) ? __popcll(m0) : (lane == 1) ? __popcll(m1) : (lane == 2) ? __popcll(m2) : __popcll(m3);
    int basev = 0;
    if (lane < 4) basev = atomicAdd(&cursor[lane], cntl);
    int base = __shfl(basev, c, 64);
    int dst = base + rank;
    perm[dst] = i;
    const float2* xr = (const float2*)(x + (size_t)i * 6);
    float2* xw = (float2*)(xp + (size_t)dst * 6);
    float2 a = xr[0], b = xr[1], cc = xr[2];
    xw[0] = a; xw[1] = b; xw[2] = cc;
}

// ---------------- encode kernel: one level per block, level -> XCD pinned ----------------
// ROOFLINE (R3-R8): bound by L2 request rate (~295 G req/s vs ~307 G ceiling); 40 req/pt-lvl
// is the algorithmic floor (3-way mask specialization). Single dispatch; grid covers all
// NCHUNK=2049 chunks including the class-padding overflow chunk. Do not touch.
__global__ __launch_bounds__(256, 4) void k_encode(
    const float* __restrict__ xp, const uint32_t* __restrict__ T,
    uint32_t* __restrict__ encP)
{
    __shared__ float xs[256 * 6];
    const int t = threadIdx.x;
    const int NC8 = NCHUNK * 8;
    const int pass = (blockIdx.x >= NC8) ? 1 : 0;
    const int rem  = blockIdx.x - pass * NC8;
    const int l    = (rem & 7) + (pass << 3);
    const int chunk = rem >> 3;
    const int pbase = chunk << 8;

    for (int idx = t; idx < 256 * 6; idx += 256) {
        float v = xp[(size_t)pbase * 6 + idx];
        xs[idx] = fminf(fmaxf(v, 0.f), 1.f);
    }
    __syncthreads();

    const float res  = RESF[l];
    const float grid = GRIDF[l];
    float wv[6]; uint32_t ua[6], ub[6];
    #pragma unroll
    for (int d = 0; d < 6; d++) {
        float xv  = xs[t * 6 + d];
        float blf = floorf(xv * res);
        float w   = (xv - blf * grid) / (grid + 1e-6f);
        wv[d] = fminf(fmaxf(w, 0.f), 1.f);
        uint32_t uu = (uint32_t)(int)blf * PRS[d];
        ua[d] = uu; ub[d] = uu + PRS[d];
    }
    uint32_t HK[4]; float WK[4];
    #pragma unroll
    for (int q = 0; q < 4; q++) {
        const int b1 = (q >> 1) & 1, bb = q & 1;
        HK[q] = (b1 ? ub[4] : ua[4]) ^ (bb ? ub[5] : ua[5]);
        WK[q] = (bb ? wv[0] : 1.f - wv[0]) * (b1 ? wv[1] : 1.f - wv[1]);
    }
    uint32_t S8[8]; float W8[8];
    #pragma unroll
    for (int jj = 0; jj < 8; jj++) {
        const int j1 = jj >> 2, j = jj & 3;
        const int b1 = (j >> 1) & 1, bb = j & 1;
        const uint32_t hj = (b1 ? ub[2] : ua[2]) ^ (bb ? ub[3] : ua[3]);
        const float  wj = ((bb ? wv[2] : 1.f - wv[2]) * (b1 ? wv[3] : 1.f - wv[3]));
        S8[jj] = (j1 ? ub[1] : ua[1]) ^ hj;
        W8[jj] = (j1 ? wv[4] : 1.f - wv[4]) * wj;
    }
    const float w5a = 1.f - wv[5], w5b = wv[5];   // dim0 beta weights
    const uint32_t bl0  = ua[0];                  // prime = 1
    const uint32_t mask = bl0 ^ (bl0 + 1u);       // XOR delta of the dim0 vertex pair
    const uint32_t* __restrict__ Tl  = T + (size_t)l * HTABLE;
    const uint4*    __restrict__ Tl4 = reinterpret_cast<const uint4*>(Tl);

    float f0 = 0.f, f1 = 0.f;
    #pragma unroll 2
    for (int jj = 0; jj < 8; jj++) {
        const uint32_t Sj = S8[jj];
        const float   wj = W8[jj];
        #pragma unroll
        for (int k = 0; k < 4; k++) {
            const uint32_t h  = (bl0 ^ Sj ^ HK[k]) & TMASK;
            const float wS = wj * WK[k];
            uint32_t pa, pb;
            if (mask == 1u) {
                const uint2 pr = *(const uint2*)(Tl + (h & ~1u));
                pa = (h & 1u) ? pr.y : pr.x;
                pb = (h & 1u) ? pr.x : pr.y;
            } else if (mask == 3u) {
                const uint4 La = Tl4[h >> 2];
                const uint32_t i0 = h & 3u;
                pa = sel4(La, i0);
                pb = sel4(La, i0 ^ 3u);
            } else {
                pa = Tl[h];
                pb = Tl[h ^ mask];
            }
            const float e0x = __uint_as_float(pa << 16),  e0y = __uint_as_float(pa & 0xFFFF0000u);
            const float e1x = __uint_as_float(pb << 16),  e1y = __uint_as_float(pb & 0xFFFF0000u);
            f0 = fmaf(wS, fmaf(w5a, e0x, w5b * e1x), f0);
            f1 = fmaf(wS, fmaf(w5a, e0y, w5b * e1y), f1);
        }
    }
    const uint32_t val = f2bf(f0) | (f2bf(f1) << 16);
    __builtin_nontemporal_store(val, &encP[(size_t)l * BPAD + pbase + t]);
}

// ---------------- MFMA MLP — 8 waves as 4 neuron-slices x 2 point-halves ----------------
// R8 post-mortem: LDS diet/occupancy neutral (3rd falsified TLP theory). VGPR floor
// (acc+h_reg>=64) caps TLP at ~4 waves/SIMD; the dominant pipe is LDS: B-traffic/wave/layer
// = K x pts_per_wave x 2B. R6's 32n x 64p tiling: 32KB/wave/layer -> ~185us/CU of LDS pipe.
// THIS round: 64n x 32p per wave (slice s = wv>>1, half ph = wv&1): LDS traffic HALVES
// (16KB/wave/layer); cost = 2x weight L2 traffic (cached, non-saturated). acc[4][2]+
// h_reg[4][2]+Acur/Anext+Bf ~ 119 VGPR < (512,4)'s 128 cap -> no spill.
__global__ __launch_bounds__(512, 4) void k_mlp2(
    const int* __restrict__ lid, const uint32_t* __restrict__ encP,
    const uint16_t* __restrict__ W0t, const float* __restrict__ b0,
    const uint16_t* __restrict__ Wrt, const float* __restrict__ bres,
    const float* __restrict__ scales, const float* __restrict__ Wout, const float* __restrict__ bout,
    const int* __restrict__ perm, float* __restrict__ out)
{
    __shared__ uint16_t hB[64 * KSTR];        // 33792 B  H as [point][k] bf16
    __shared__ __align__(16) char smU[64 * KE * 2];  // 5120 B: encB (layer 0) UNION outP (output)
    __shared__ float    bs[256];              //  1024 B
    __shared__ int      permL[TILE];          //   256 B
    uint16_t* encB = (uint16_t*)smU;
    float*    outP = (float*)smU;             // 64 pts x 4 slices = 1024 B

    const int t  = threadIdx.x;
    const int lane = t & 63;
    const int wv = t >> 6;          // wave id 0..7
    const int s  = wv >> 1;         // neuron slice 0..3 (64 neurons)
    const int ph = wv & 1;          // point half 0..1 (32 points)
    const int mi = lane & 15;
    const int q  = lane >> 4;

    if (t < TILE) permL[t] = perm[(size_t)blockIdx.x * TILE + t];
    __syncthreads();
    const int g0 = permL[0];
    if (g0 < 0) return;
    const int c = lid[g0] & 3;

    // stage enc [point][k=2l..2l+1] and b0 — coalesced, nontemporal (read-once)
    if (t < 256) bs[t] = b0[c * 256 + t];
    for (int idx = t; idx < 16 * 64; idx += 512) {
        const int l = idx >> 6, pp = idx & 63;
        ((uint32_t*)encB)[pp * (KE / 2) + l] =
            __builtin_nontemporal_load(&encP[(size_t)l * BPAD + (size_t)blockIdx.x * TILE + pp]);
    }
    __syncthreads();

    floatx4 acc[4][2];
    floatx4 h_reg[4][2];

    // ---- layer 0: D = W0^T(256x32) . enc(32x64); wave covers neurons [s*64,s*64+64) x pts [ph*32,ph*32+32)
    {
        #pragma unroll
        for (int mt = 0; mt < 4; mt++)
            #pragma unroll
            for (int nt = 0; nt < 2; nt++) acc[mt][nt] = (floatx4){0.f, 0.f, 0.f, 0.f};
        const short8* Wp = (const short8*)(W0t + (size_t)c * 8192);
        short8 A[4], Bf[2];
        #pragma unroll
        for (int mt = 0; mt < 4; mt++) A[mt] = Wp[(s * 64 + mt * 16 + mi) * 4 + q];
        #pragma unroll
        for (int nt = 0; nt < 2; nt++) Bf[nt] = *(const short8*)&encB[(ph * 32 + nt * 16 + mi) * KE + q * 8];
        #pragma unroll
        for (int mt = 0; mt < 4; mt++)
            #pragma unroll
            for (int nt = 0; nt < 2; nt++)
                acc[mt][nt] = __builtin_amdgcn_mfma_f32_16x16x32_bf16(A[mt], Bf[nt], acc[mt][nt], 0, 0, 0);
        // h = relu(u + b0); write bf16 to hB
        #pragma unroll
        for (int mt = 0; mt < 4; mt++) {
            const int nb = s * 64 + mt * 16 + q * 4;
            #pragma unroll
            for (int nt = 0; nt < 2; nt++) {
                floatx4 u = acc[mt][nt], h;
                h[0] = relu_(u[0] + bs[nb + 0]); h[1] = relu_(u[1] + bs[nb + 1]);
                h[2] = relu_(u[2] + bs[nb + 2]); h[3] = relu_(u[3] + bs[nb + 3]);
                h_reg[mt][nt] = h;
                uint2 pk; pk.x = f2bf(h[0]) | (f2bf(h[1]) << 16); pk.y = f2bf(h[2]) | (f2bf(h[3]) << 16);
                *(uint2*)&hB[(ph * 32 + nt * 16 + mi) * KSTR + nb] = pk;
            }
        }
    }
    __syncthreads();

    // ---- 3 scaled residual blocks
    #pragma unroll 1
    for (int ib = 0; ib < 3; ib++) {
        if (t < 256) bs[t] = bres[(size_t)((c * 3 + ib) << 8) + t];
        const float sc = scales[c * 3 + ib];
        #pragma unroll
        for (int mt = 0; mt < 4; mt++)
            #pragma unroll
            for (int nt = 0; nt < 2; nt++) acc[mt][nt] = (floatx4){0.f, 0.f, 0.f, 0.f};

        const short8* Wp = (const short8*)(Wrt + (size_t)(c * 3 + ib) * 65536);
        short8 Acur[4], Anext[4], Bf[2];
        #pragma unroll
        for (int mt = 0; mt < 4; mt++) Acur[mt] = Wp[(s * 64 + mt * 16 + mi) * 32 + q];
        #pragma unroll 1
        for (int ks = 0; ks < 8; ks++) {
            #pragma unroll
            for (int nt = 0; nt < 2; nt++)
                Bf[nt] = *(const short8*)&hB[(ph * 32 + nt * 16 + mi) * KSTR + ks * 32 + q * 8];
            if (ks < 7) {
                #pragma unroll
                for (int mt = 0; mt < 4; mt++)
                    Anext[mt] = Wp[(s * 64 + mt * 16 + mi) * 32 + (ks + 1) * 4 + q];
            }
            #pragma unroll
            for (int mt = 0; mt < 4; mt++)
                #pragma unroll
                for (int nt = 0; nt < 2; nt++)
                    acc[mt][nt] = __builtin_amdgcn_mfma_f32_16x16x32_bf16(Acur[mt], Bf[nt], acc[mt][nt], 0, 0, 0);
            #pragma unroll
            for (int mt = 0; mt < 4; mt++) Acur[mt] = Anext[mt];
        }
        __syncthreads();   // hB reads done; bs staged
        #pragma unroll
        for (int mt = 0; mt < 4; mt++) {
            const int nb = s * 64 + mt * 16 + q * 4;
            #pragma unroll
            for (int nt = 0; nt < 2; nt++) {
                floatx4 u = acc[mt][nt];
                floatx4 h = h_reg[mt][nt];
                h[0] = fmaf(sc, relu_(u[0] + bs[nb + 0]), h[0]);
                h[1] = fmaf(sc, relu_(u[1] + bs[nb + 1]), h[1]);
                h[2] = fmaf(sc, relu_(u[2] + bs[nb + 2]), h[2]);
                h[3] = fmaf(sc, relu_(u[3] + bs[nb + 3]), h[3]);
                h_reg[mt][nt] = h;
                if (ib < 2) {
                    uint2 pk; pk.x = f2bf(h[0]) | (f2bf(h[1]) << 16); pk.y = f2bf(h[2]) | (f2bf(h[3]) << 16);
                    *(uint2*)&hB[(ph * 32 + nt * 16 + mi) * KSTR + nb] = pk;
                }
            }
        }
        if (ib < 2) __syncthreads();
    }

    // ---- output layer: out[p] = sum_n h[n][p] * Wout[n] + bout
    __syncthreads();                 // hB/encB use done; smU safe for outP
    if (t < 256) bs[t] = Wout[c * 256 + t];
    __syncthreads();
    float po[2] = {0.f, 0.f};
    #pragma unroll
    for (int mt = 0; mt < 4; mt++) {
        const int nb = s * 64 + mt * 16 + q * 4;
        const float w0v = bs[nb + 0], w1v = bs[nb + 1], w2v = bs[nb + 2], w3v = bs[nb + 3];
        #pragma unroll
        for (int nt = 0; nt < 2; nt++) {
            const floatx4 h = h_reg[mt][nt];
            po[nt] += h[0] * w0v + h[1] * w1v + h[2] * w2v + h[3] * w3v;
        }
    }
    #pragma unroll
    for (int nt = 0; nt < 2; nt++) {
        float v = po[nt];
        v += __shfl_xor(v, 16, 64);
        v += __shfl_xor(v, 32, 64);
        if (q == 0) outP[(ph * 32 + nt * 16 + mi) * 4 + s] = v;   // [point][slice]
    }
    __syncthreads();
    if (t < TILE) {
        const float4 p4 = *(const float4*)&outP[t * 4];
        float r = p4.x + p4.y + p4.z + p4.w + bout[c];
        const int gi = permL[t];
        if (gi >= 0) out[gi] = r;
    }
}

extern "C" void kernel_launch(void* const* d_in, const int* in_sizes, int n_in,
                              void* d_out, int out_size, void* d_ws, size_t ws_size,
                              hipStream_t stream) {
    const float* x      = (const float*)d_in[0];
    const int*   lid    = (const int*)  d_in[1];
    const float* emb    = (const float*)d_in[2];
    const float* W0     = (const float*)d_in[3];
    const float* b0     = (const float*)d_in[4];
    const float* Wres   = (const float*)d_in[5];
    const float* bres   = (const float*)d_in[6];
    const float* scales = (const float*)d_in[7];
    const float* Wout   = (const float*)d_in[8];
    const float* bout   = (const float*)d_in[9];
    float* out = (float*)d_out;

    const int B = in_sizes[1];                          // 524288 points
    // workspace layout (~82.6 MB):
    int* cnt    = (int*)d_ws;                                        // [0,16)
    int* cursor = cnt + 4;                                           // [16,32)
    int*      perm = (int*)((char*)d_ws + 16384);                    // 2.0 MB padded permutation
    uint16_t* W0t  = (uint16_t*)((char*)d_ws + 2228224);             // 64 KB
    uint16_t* Wrt  = (uint16_t*)((char*)d_ws + 2359296);             // 1.5 MB
    uint32_t* encP = (uint32_t*)((char*)d_ws + (4ull  << 20));       // 4MB..37.6MB  [16][BPAD] bf16 pairs
    uint32_t* T    = (uint32_t*)((char*)d_ws + (38ull << 20));       // 38..70MB     bf16 pair table
    float*    xp   = (float*)   ((char*)d_ws + (70ull << 20));       // 70..82.6MB   permuted coords

    (void)hipMemsetAsync(d_ws, 0, 64, stream);
    k_fusedprep<<<PACK_N + PREP_N + COUNT_N + PERM_N, 256, 0, stream>>>(
        emb, T, Wres, W0, Wrt, W0t, lid, B, cnt, perm);
    k_offsets<<<1, 64, 0, stream>>>(cnt, cursor);
    k_scatter<<<B / 256, 256, 0, stream>>>(lid, x, B, cursor, perm, xp);
    k_encode <<<NCHUNK * 16, 256, 0, stream>>>(xp, T, encP);
    k_mlp2   <<<NTILE, 512, 0, stream>>>(lid, encP, W0t, b0, Wrt, bres, scales, Wout, bout, perm, out);
}

// Round 11
// 1739.746 us; speedup vs baseline: 1.1896x; 1.1896x over previous
//
#include <hip/hip_runtime.h>
#include <hip/hip_bf16.h>
#include <stdint.h>

#define HTABLE (1u << 19)
#define TMASK  (HTABLE - 1u)
#define TILE   64
#define KSTR   264   // hB row stride in bf16 elems (528 B)
#define KE     40    // encB row stride in bf16 elems

#define NTILE   8196               // 64-pt mlp tiles (= NCHUNK*4)
#define NCHUNK  2049               // 256-pt chunks of the permuted stream (INCLUDES overflow chunk)
#define BPAD    (NCHUNK * 256)     // padded point count 524544

typedef __attribute__((ext_vector_type(8))) short short8;
typedef __attribute__((ext_vector_type(4))) float floatx4;

__device__ __forceinline__ float relu_(float v) { return fmaxf(v, 0.f); }

__device__ __forceinline__ uint32_t f2bf(float f) {
    uint32_t u = __float_as_uint(f);
    return (u + 0x7FFFu + ((u >> 16) & 1u)) >> 16;
}

// packed f32x2 -> bf16x2 (RNE, identical to f2bf pair): lowers to v_cvt_pk_bf16_f32
__device__ __forceinline__ uint32_t pk_bf16(float a, float b) {
    __hip_bfloat162 v = __float22bfloat162_rn(float2{a, b});
    return *reinterpret_cast<uint32_t*>(&v);
}

// variable-index extract from a 16B quad: 3 cndmasks, no scratch
__device__ __forceinline__ uint32_t sel4(const uint4& v, uint32_t i) {
    uint32_t lo = (i & 1u) ? v.y : v.x;
    uint32_t hi = (i & 1u) ? v.w : v.z;
    return (i & 2u) ? hi : lo;
}

__device__ __constant__ uint32_t PRS[6] = {1u, 2654435761u, 805459861u, 3674653429u, 2097192037u, 1434869437u};
__device__ __constant__ float RESF[16]  = {16.f,20.f,25.f,32.f,40.f,50.f,64.f,80.f,101.f,128.f,161.f,203.f,256.f,322.f,406.f,512.f};
__device__ __constant__ float GRIDF[16] = {1.f/16.f,1.f/20.f,1.f/25.f,1.f/32.f,1.f/40.f,1.f/50.f,1.f/64.f,1.f/80.f,
                                           1.f/101.f,1.f/128.f,1.f/161.f,1.f/203.f,1.f/256.f,1.f/322.f,1.f/406.f,1.f/512.f};

// ---------------- binning kernels ----------------
__global__ void k_count(const int* __restrict__ lid, int n, int* __restrict__ cnt) {
    __shared__ int h4[4];
    int i = blockIdx.x * blockDim.x + threadIdx.x;
    if (threadIdx.x < 4) h4[threadIdx.x] = 0;
    __syncthreads();
    if (i < n) atomicAdd(&h4[lid[i] & 3], 1);
    __syncthreads();
    if (threadIdx.x < 4) atomicAdd(&cnt[threadIdx.x], h4[threadIdx.x]);
}

__global__ void k_offsets(const int* __restrict__ cnt, int* __restrict__ cursor) {
    if (threadIdx.x == 0 && blockIdx.x == 0) {
        int off = 0;
        for (int k = 0; k < 4; k++) {
            cursor[k] = off;
            off = (off + cnt[k] + 63) & ~63;
        }
    }
}

// scatter: class-sorted perm AND the permuted coordinate stream xp[j] = x[perm[j]]
__global__ void k_scatter(const int* __restrict__ lid, const float* __restrict__ x, int n,
                          int* __restrict__ cursor, int* __restrict__ perm, float* __restrict__ xp) {
    int i = blockIdx.x * blockDim.x + threadIdx.x;
    if (i >= n) return;
    int lane = threadIdx.x & 63;
    int c = lid[i] & 3;
    unsigned long long m0 = __ballot(c == 0), m1 = __ballot(c == 1);
    unsigned long long m2 = __ballot(c == 2), m3 = __ballot(c == 3);
    unsigned long long mc = (c == 0) ? m0 : (c == 1) ? m1 : (c == 2) ? m2 : m3;
    int rank = __popcll(mc & ((1ull << lane) - 1ull));
    int cntl = (lane == 0) ? __popcll(m0) : (lane == 1) ? __popcll(m1) : (lane == 2) ? __popcll(m2) : __popcll(m3);
    int basev = 0;
    if (lane < 4) basev = atomicAdd(&cursor[lane], cntl);
    int base = __shfl(basev, c, 64);
    int dst = base + rank;
    perm[dst] = i;
    const float2* xr = (const float2*)(x + (size_t)i * 6);
    float2* xw = (float2*)(xp + (size_t)dst * 6);
    float2 a = xr[0], b = xr[1], cc = xr[2];
    xw[0] = a; xw[1] = b; xw[2] = cc;
}

// ---------------- pack embedding table to bf16: T[l][g] = (bf16(e.x), bf16(e.y)) ----------------
__global__ __launch_bounds__(256) void k_packtab(const float* __restrict__ emb, uint32_t* __restrict__ T) {
    const int i = blockIdx.x * 256 + threadIdx.x;
    float2 e = ((const float2*)emb)[i];
    T[i] = f2bf(e.x) | (f2bf(e.y) << 16);
}

// ---------------- weight prep: transpose + bf16 ----------------
__global__ __launch_bounds__(256) void k_prep(const float* __restrict__ Wres, const float* __restrict__ W0,
                                              uint16_t* __restrict__ Wrt, uint16_t* __restrict__ W0t) {
    __shared__ float sm[64 * 65 > 32 * 257 ? 64 * 65 : 32 * 257];
    const int t = threadIdx.x;
    const int bid = blockIdx.x;
    if (bid < 192) {
        const int c = bid / 48, rem = bid % 48, ib = rem / 16, tile = rem % 16;
        const int n0 = (tile / 4) * 64, k0 = (tile % 4) * 64;
        const float* src = Wres + (size_t)(c * 3 + ib) * 65536;
        for (int i = 0; i < 16; i++) {
            int idx = t + 256 * i, r = idx >> 6, cc = idx & 63;
            sm[r * 65 + cc] = src[(size_t)(k0 + r) * 256 + n0 + cc];
        }
        __syncthreads();
        uint16_t* dst = Wrt + (size_t)(c * 3 + ib) * 65536;
        for (int i = 0; i < 16; i++) {
            int idx = t + 256 * i, rn = idx >> 6, ck = idx & 63;
            dst[(size_t)(n0 + rn) * 256 + k0 + ck] = (uint16_t)f2bf(sm[ck * 65 + rn]);
        }
    } else {
        const int c = bid - 192;
        for (int i = 0; i < 32; i++) {
            int idx = t + 256 * i, k = idx >> 8, n = idx & 255;
            sm[k * 257 + n] = W0[(size_t)c * 8192 + idx];
        }
        __syncthreads();
        for (int i = 0; i < 32; i++) {
            int idx = t + 256 * i, n = idx >> 5, k = idx & 31;
            W0t[(size_t)c * 8192 + idx] = (uint16_t)f2bf(sm[k * 257 + n]);
        }
    }
}

// ---------------- encode kernel: one level per block, level -> XCD pinned ----------------
// ROOFLINE (R3-R8): bound by L2 request rate (~295 G req/s vs ~307 G ceiling); 40 req/pt-lvl
// is the algorithmic floor (3-way mask specialization). Grid covers all NCHUNK=2049 chunks
// including the class-padding overflow chunk. Do not touch.
__global__ __launch_bounds__(256, 4) void k_encode(
    const float* __restrict__ xp, const uint32_t* __restrict__ T,
    uint32_t* __restrict__ encP)
{
    __shared__ float xs[256 * 6];
    const int t = threadIdx.x;
    const int NC8 = NCHUNK * 8;
    const int pass = (blockIdx.x >= NC8) ? 1 : 0;
    const int rem  = blockIdx.x - pass * NC8;
    const int l    = (rem & 7) + (pass << 3);
    const int chunk = rem >> 3;
    const int pbase = chunk << 8;

    for (int idx = t; idx < 256 * 6; idx += 256) {
        float v = xp[(size_t)pbase * 6 + idx];
        xs[idx] = fminf(fmaxf(v, 0.f), 1.f);
    }
    __syncthreads();

    const float res  = RESF[l];
    const float grid = GRIDF[l];
    float wv[6]; uint32_t ua[6], ub[6];
    #pragma unroll
    for (int d = 0; d < 6; d++) {
        float xv  = xs[t * 6 + d];
        float blf = floorf(xv * res);
        float w   = (xv - blf * grid) / (grid + 1e-6f);
        wv[d] = fminf(fmaxf(w, 0.f), 1.f);
        uint32_t uu = (uint32_t)(int)blf * PRS[d];
        ua[d] = uu; ub[d] = uu + PRS[d];
    }
    uint32_t HK[4]; float WK[4];
    #pragma unroll
    for (int q = 0; q < 4; q++) {
        const int b1 = (q >> 1) & 1, bb = q & 1;
        HK[q] = (b1 ? ub[4] : ua[4]) ^ (bb ? ub[5] : ua[5]);
        WK[q] = (bb ? wv[0] : 1.f - wv[0]) * (b1 ? wv[1] : 1.f - wv[1]);
    }
    uint32_t S8[8]; float W8[8];
    #pragma unroll
    for (int jj = 0; jj < 8; jj++) {
        const int j1 = jj >> 2, j = jj & 3;
        const int b1 = (j >> 1) & 1, bb = j & 1;
        const uint32_t hj = (b1 ? ub[2] : ua[2]) ^ (bb ? ub[3] : ua[3]);
        const float  wj = ((bb ? wv[2] : 1.f - wv[2]) * (b1 ? wv[3] : 1.f - wv[3]));
        S8[jj] = (j1 ? ub[1] : ua[1]) ^ hj;
        W8[jj] = (j1 ? wv[4] : 1.f - wv[4]) * wj;
    }
    const float w5a = 1.f - wv[5], w5b = wv[5];   // dim0 beta weights
    const uint32_t bl0  = ua[0];                  // prime = 1
    const uint32_t mask = bl0 ^ (bl0 + 1u);       // XOR delta of the dim0 vertex pair
    const uint32_t* __restrict__ Tl  = T + (size_t)l * HTABLE;
    const uint4*    __restrict__ Tl4 = reinterpret_cast<const uint4*>(Tl);

    float f0 = 0.f, f1 = 0.f;
    #pragma unroll 2
    for (int jj = 0; jj < 8; jj++) {
        const uint32_t Sj = S8[jj];
        const float   wj = W8[jj];
        #pragma unroll
        for (int k = 0; k < 4; k++) {
            const uint32_t h  = (bl0 ^ Sj ^ HK[k]) & TMASK;
            const float wS = wj * WK[k];
            uint32_t pa, pb;
            if (mask == 1u) {
                const uint2 pr = *(const uint2*)(Tl + (h & ~1u));
                pa = (h & 1u) ? pr.y : pr.x;
                pb = (h & 1u) ? pr.x : pr.y;
            } else if (mask == 3u) {
                const uint4 La = Tl4[h >> 2];
                const uint32_t i0 = h & 3u;
                pa = sel4(La, i0);
                pb = sel4(La, i0 ^ 3u);
            } else {
                pa = Tl[h];
                pb = Tl[h ^ mask];
            }
            const float e0x = __uint_as_float(pa << 16),  e0y = __uint_as_float(pa & 0xFFFF0000u);
            const float e1x = __uint_as_float(pb << 16),  e1y = __uint_as_float(pb & 0xFFFF0000u);
            f0 = fmaf(wS, fmaf(w5a, e0x, w5b * e1x), f0);
            f1 = fmaf(wS, fmaf(w5a, e0y, w5b * e1y), f1);
        }
    }
    const uint32_t val = f2bf(f0) | (f2bf(f1) << 16);
    __builtin_nontemporal_store(val, &encP[(size_t)l * BPAD + pbase + t]);
}

// ---------------- MFMA MLP — 8-wave / 32-neuron-per-wave (R8 config, best known) ----------------
// R9 post-mortem: 64nx32p retile doubled weight L2 traffic (-90us) and sat at the 128-reg
// cap; reverted. Occupancy is reg-file-bound (60 VGPR + 64 AGPR = 124/wave -> 4 waves/SIMD
// structural). R10/11 change: epilogue bf16 packing via v_cvt_pk_bf16_f32 (pk_bf16, RNE ==
// f2bf) — cuts ~25us off the largest pipe (VALU 29%).
__global__ __launch_bounds__(512, 4) void k_mlp2(
    const int* __restrict__ lid, const uint32_t* __restrict__ encP,
    const uint16_t* __restrict__ W0t, const float* __restrict__ b0,
    const uint16_t* __restrict__ Wrt, const float* __restrict__ bres,
    const float* __restrict__ scales, const float* __restrict__ Wout, const float* __restrict__ bout,
    const int* __restrict__ perm, float* __restrict__ out)
{
    __shared__ uint16_t hB[64 * KSTR];        // 33792 B  H as [point][k] bf16
    __shared__ __align__(16) char smU[64 * KE * 2];  // 5120 B: encB (layer 0) UNION outP (output)
    __shared__ float    bs[256];              //  1024 B
    __shared__ int      permL[TILE];          //   256 B
    uint16_t* encB = (uint16_t*)smU;
    float*    outP = (float*)smU;

    const int t  = threadIdx.x;
    const int lane = t & 63;
    const int wv = t >> 6;          // wave id 0..7: 32-neuron slice
    const int mi = lane & 15;
    const int q  = lane >> 4;

    if (t < TILE) permL[t] = perm[(size_t)blockIdx.x * TILE + t];
    __syncthreads();
    const int g0 = permL[0];
    if (g0 < 0) return;
    const int c = lid[g0] & 3;

    // stage enc [point][k=2l..2l+1] and b0 — coalesced, nontemporal (read-once)
    if (t < 256) bs[t] = b0[c * 256 + t];
    for (int idx = t; idx < 16 * 64; idx += 512) {
        const int l = idx >> 6, pp = idx & 63;
        ((uint32_t*)encB)[pp * (KE / 2) + l] =
            __builtin_nontemporal_load(&encP[(size_t)l * BPAD + (size_t)blockIdx.x * TILE + pp]);
    }
    __syncthreads();

    floatx4 acc[2][4];
    floatx4 h_reg[2][4];

    // ---- layer 0: D = W0^T(256x32) . enc(32x64); wave wv covers neurons [wv*32, wv*32+32)
    {
        #pragma unroll
        for (int mt = 0; mt < 2; mt++)
            #pragma unroll
            for (int nt = 0; nt < 4; nt++) acc[mt][nt] = (floatx4){0.f, 0.f, 0.f, 0.f};
        const short8* Wp = (const short8*)(W0t + (size_t)c * 8192);
        short8 A[2], Bf[4];
        #pragma unroll
        for (int mt = 0; mt < 2; mt++) A[mt] = Wp[(wv * 32 + mt * 16 + mi) * 4 + q];
        #pragma unroll
        for (int nt = 0; nt < 4; nt++) Bf[nt] = *(const short8*)&encB[(nt * 16 + mi) * KE + q * 8];
        #pragma unroll
        for (int mt = 0; mt < 2; mt++)
            #pragma unroll
            for (int nt = 0; nt < 4; nt++)
                acc[mt][nt] = __builtin_amdgcn_mfma_f32_16x16x32_bf16(A[mt], Bf[nt], acc[mt][nt], 0, 0, 0);
        #pragma unroll
        for (int mt = 0; mt < 2; mt++) {
            const int nb = wv * 32 + mt * 16 + q * 4;
            #pragma unroll
            for (int nt = 0; nt < 4; nt++) {
                floatx4 u = acc[mt][nt], h;
                h[0] = relu_(u[0] + bs[nb + 0]); h[1] = relu_(u[1] + bs[nb + 1]);
                h[2] = relu_(u[2] + bs[nb + 2]); h[3] = relu_(u[3] + bs[nb + 3]);
                h_reg[mt][nt] = h;
                uint2 pk; pk.x = pk_bf16(h[0], h[1]); pk.y = pk_bf16(h[2], h[3]);
                *(uint2*)&hB[(nt * 16 + mi) * KSTR + nb] = pk;
            }
        }
    }
    __syncthreads();

    // ---- 3 scaled residual blocks
    #pragma unroll 1
    for (int ib = 0; ib < 3; ib++) {
        if (t < 256) bs[t] = bres[(size_t)((c * 3 + ib) << 8) + t];
        const float s = scales[c * 3 + ib];
        #pragma unroll
        for (int mt = 0; mt < 2; mt++)
            #pragma unroll
            for (int nt = 0; nt < 4; nt++) acc[mt][nt] = (floatx4){0.f, 0.f, 0.f, 0.f};

        const short8* Wp = (const short8*)(Wrt + (size_t)(c * 3 + ib) * 65536);
        short8 Acur[2], Anext[2], Bf[4];
        #pragma unroll
        for (int mt = 0; mt < 2; mt++) Acur[mt] = Wp[(wv * 32 + mt * 16 + mi) * 32 + q];
        #pragma unroll 1
        for (int ks = 0; ks < 8; ks++) {
            #pragma unroll
            for (int nt = 0; nt < 4; nt++)
                Bf[nt] = *(const short8*)&hB[(nt * 16 + mi) * KSTR + ks * 32 + q * 8];
            if (ks < 7) {
                #pragma unroll
                for (int mt = 0; mt < 2; mt++)
                    Anext[mt] = Wp[(wv * 32 + mt * 16 + mi) * 32 + (ks + 1) * 4 + q];
            }
            #pragma unroll
            for (int mt = 0; mt < 2; mt++)
                #pragma unroll
                for (int nt = 0; nt < 4; nt++)
                    acc[mt][nt] = __builtin_amdgcn_mfma_f32_16x16x32_bf16(Acur[mt], Bf[nt], acc[mt][nt], 0, 0, 0);
            #pragma unroll
            for (int mt = 0; mt < 2; mt++) Acur[mt] = Anext[mt];
        }
        __syncthreads();   // hB reads done; bs staged
        #pragma unroll
        for (int mt = 0; mt < 2; mt++) {
            const int nb = wv * 32 + mt * 16 + q * 4;
            #pragma unroll
            for (int nt = 0; nt < 4; nt++) {
                floatx4 u = acc[mt][nt];
                floatx4 h = h_reg[mt][nt];
                h[0] = fmaf(s, relu_(u[0] + bs[nb + 0]), h[0]);
                h[1] = fmaf(s, relu_(u[1] + bs[nb + 1]), h[1]);
                h[2] = fmaf(s, relu_(u[2] + bs[nb + 2]), h[2]);
                h[3] = fmaf(s, relu_(u[3] + bs[nb + 3]), h[3]);
                h_reg[mt][nt] = h;
                if (ib < 2) {
                    uint2 pk; pk.x = pk_bf16(h[0], h[1]); pk.y = pk_bf16(h[2], h[3]);
                    *(uint2*)&hB[(nt * 16 + mi) * KSTR + nb] = pk;
                }
            }
        }
        if (ib < 2) __syncthreads();
    }

    // ---- output layer: out[p] = sum_n h[n][p] * Wout[n] + bout
    __syncthreads();                 // hB/encB use done; smU safe for outP
    if (t < 256) bs[t] = Wout[c * 256 + t];
    __syncthreads();
    float po[4] = {0.f, 0.f, 0.f, 0.f};
    #pragma unroll
    for (int mt = 0; mt < 2; mt++) {
        const int nb = wv * 32 + mt * 16 + q * 4;
        const float w0v = bs[nb + 0], w1v = bs[nb + 1], w2v = bs[nb + 2], w3v = bs[nb + 3];
        #pragma unroll
        for (int nt = 0; nt < 4; nt++) {
            const floatx4 h = h_reg[mt][nt];
            po[nt] += h[0] * w0v + h[1] * w1v + h[2] * w2v + h[3] * w3v;
        }
    }
    #pragma unroll
    for (int nt = 0; nt < 4; nt++) {
        float v = po[nt];
        v += __shfl_xor(v, 16, 64);
        v += __shfl_xor(v, 32, 64);
        if (q == 0) outP[wv * 64 + nt * 16 + mi] = v;
    }
    __syncthreads();
    if (t < TILE) {
        float r = outP[t]       + outP[64 + t]  + outP[128 + t] + outP[192 + t]
                + outP[256 + t] + outP[320 + t] + outP[384 + t] + outP[448 + t] + bout[c];
        const int gi = permL[t];
        if (gi >= 0) out[gi] = r;
    }
}

extern "C" void kernel_launch(void* const* d_in, const int* in_sizes, int n_in,
                              void* d_out, int out_size, void* d_ws, size_t ws_size,
                              hipStream_t stream) {
    const float* x      = (const float*)d_in[0];
    const int*   lid    = (const int*)  d_in[1];
    const float* emb    = (const float*)d_in[2];
    const float* W0     = (const float*)d_in[3];
    const float* b0     = (const float*)d_in[4];
    const float* Wres   = (const float*)d_in[5];
    const float* bres   = (const float*)d_in[6];
    const float* scales = (const float*)d_in[7];
    const float* Wout   = (const float*)d_in[8];
    const float* bout   = (const float*)d_in[9];
    float* out = (float*)d_out;

    const int B = in_sizes[1];                          // 524288 points
    // workspace layout (~82.6 MB):
    int* cnt    = (int*)d_ws;                                        // [0,16)
    int* cursor = cnt + 4;                                           // [16,32)
    int*      perm = (int*)((char*)d_ws + 16384);                    // 2.0 MB padded permutation
    uint16_t* W0t  = (uint16_t*)((char*)d_ws + 2228224);             // 64 KB
    uint16_t* Wrt  = (uint16_t*)((char*)d_ws + 2359296);             // 1.5 MB
    uint32_t* encP = (uint32_t*)((char*)d_ws + (4ull  << 20));       // 4MB..37.6MB  [16][BPAD] bf16 pairs
    uint32_t* T    = (uint32_t*)((char*)d_ws + (38ull << 20));       // 38..70MB     bf16 pair table
    float*    xp   = (float*)   ((char*)d_ws + (70ull << 20));       // 70..82.6MB   permuted coords

    (void)hipMemsetAsync(d_ws, 0, 64, stream);
    (void)hipMemsetAsync(perm, 0xFF, (size_t)NTILE * TILE * sizeof(int), stream);
    k_packtab<<<(16 * (int)HTABLE) / 256, 256, 0, stream>>>(emb, T);
    k_prep   <<<196, 256, 0, stream>>>(Wres, W0, Wrt, W0t);
    k_count  <<<B / 256, 256, 0, stream>>>(lid, B, cnt);
    k_offsets<<<1, 64, 0, stream>>>(cnt, cursor);
    k_scatter<<<B / 256, 256, 0, stream>>>(lid, x, B, cursor, perm, xp);
    k_encode <<<NCHUNK * 16, 256, 0, stream>>>(xp, T, encP);
    k_mlp2   <<<NTILE, 512, 0, stream>>>(lid, encP, W0t, b0, Wrt, bres, scales, Wout, bout, perm, out);
}

// Round 12
// 1724.511 us; speedup vs baseline: 1.2001x; 1.0088x over previous
//
#include <hip/hip_runtime.h>
#include <hip/hip_bf16.h>
#include <stdint.h>

#define HTABLE (1u << 19)
#define TMASK  (HTABLE - 1u)
#define TILE   64
#define KSTR   264   // hB row stride in bf16 elems (528 B)
#define KE     40    // encB row stride in bf16 elems

#define NTILE   8196               // 64-pt mlp tiles (= NCHUNK*4)
#define NCHUNK  2049               // 256-pt chunks of the permuted stream (INCLUDES overflow chunk)
#define BPAD    (NCHUNK * 256)     // padded point count 524544

typedef __attribute__((ext_vector_type(8))) short short8;
typedef __attribute__((ext_vector_type(4))) float floatx4;

__device__ __forceinline__ float relu_(float v) { return fmaxf(v, 0.f); }

__device__ __forceinline__ uint32_t f2bf(float f) {
    uint32_t u = __float_as_uint(f);
    return (u + 0x7FFFu + ((u >> 16) & 1u)) >> 16;
}

// packed f32x2 -> bf16x2 (RNE, identical to f2bf pair): lowers to v_cvt_pk_bf16_f32
__device__ __forceinline__ uint32_t pk_bf16(float a, float b) {
    __hip_bfloat162 v = __float22bfloat162_rn(float2{a, b});
    return *reinterpret_cast<uint32_t*>(&v);
}

// variable-index extract from a 16B quad: 3 cndmasks, no scratch
__device__ __forceinline__ uint32_t sel4(const uint4& v, uint32_t i) {
    uint32_t lo = (i & 1u) ? v.y : v.x;
    uint32_t hi = (i & 1u) ? v.w : v.z;
    return (i & 2u) ? hi : lo;
}

__device__ __constant__ uint32_t PRS[6] = {1u, 2654435761u, 805459861u, 3674653429u, 2097192037u, 1434869437u};
__device__ __constant__ float RESF[16]  = {16.f,20.f,25.f,32.f,40.f,50.f,64.f,80.f,101.f,128.f,161.f,203.f,256.f,322.f,406.f,512.f};
__device__ __constant__ float GRIDF[16] = {1.f/16.f,1.f/20.f,1.f/25.f,1.f/32.f,1.f/40.f,1.f/50.f,1.f/64.f,1.f/80.f,
                                           1.f/101.f,1.f/128.f,1.f/161.f,1.f/203.f,1.f/256.f,1.f/322.f,1.f/406.f,1.f/512.f};

// ---------------- binning kernels ----------------
__global__ void k_count(const int* __restrict__ lid, int n, int* __restrict__ cnt) {
    __shared__ int h4[4];
    int i = blockIdx.x * blockDim.x + threadIdx.x;
    if (threadIdx.x < 4) h4[threadIdx.x] = 0;
    __syncthreads();
    if (i < n) atomicAdd(&h4[lid[i] & 3], 1);
    __syncthreads();
    if (threadIdx.x < 4) atomicAdd(&cnt[threadIdx.x], h4[threadIdx.x]);
}

__global__ void k_offsets(const int* __restrict__ cnt, int* __restrict__ cursor) {
    if (threadIdx.x == 0 && blockIdx.x == 0) {
        int off = 0;
        for (int k = 0; k < 4; k++) {
            cursor[k] = off;
            off = (off + cnt[k] + 63) & ~63;
        }
    }
}

// scatter: class-sorted perm AND the permuted coordinate stream xp[j] = x[perm[j]]
__global__ void k_scatter(const int* __restrict__ lid, const float* __restrict__ x, int n,
                          int* __restrict__ cursor, int* __restrict__ perm, float* __restrict__ xp) {
    int i = blockIdx.x * blockDim.x + threadIdx.x;
    if (i >= n) return;
    int lane = threadIdx.x & 63;
    int c = lid[i] & 3;
    unsigned long long m0 = __ballot(c == 0), m1 = __ballot(c == 1);
    unsigned long long m2 = __ballot(c == 2), m3 = __ballot(c == 3);
    unsigned long long mc = (c == 0) ? m0 : (c == 1) ? m1 : (c == 2) ? m2 : m3;
    int rank = __popcll(mc & ((1ull << lane) - 1ull));
    int cntl = (lane == 0) ? __popcll(m0) : (lane == 1) ? __popcll(m1) : (lane == 2) ? __popcll(m2) : __popcll(m3);
    int basev = 0;
    if (lane < 4) basev = atomicAdd(&cursor[lane], cntl);
    int base = __shfl(basev, c, 64);
    int dst = base + rank;
    perm[dst] = i;
    const float2* xr = (const float2*)(x + (size_t)i * 6);
    float2* xw = (float2*)(xp + (size_t)dst * 6);
    float2 a = xr[0], b = xr[1], cc = xr[2];
    xw[0] = a; xw[1] = b; xw[2] = cc;
}

// ---------------- pack embedding table to bf16: T[l][g] = (bf16(e.x), bf16(e.y)) ----------------
__global__ __launch_bounds__(256) void k_packtab(const float* __restrict__ emb, uint32_t* __restrict__ T) {
    const int i = blockIdx.x * 256 + threadIdx.x;
    float2 e = ((const float2*)emb)[i];
    T[i] = f2bf(e.x) | (f2bf(e.y) << 16);
}

// ---------------- weight prep: transpose + bf16 ----------------
__global__ __launch_bounds__(256) void k_prep(const float* __restrict__ Wres, const float* __restrict__ W0,
                                              uint16_t* __restrict__ Wrt, uint16_t* __restrict__ W0t) {
    __shared__ float sm[64 * 65 > 32 * 257 ? 64 * 65 : 32 * 257];
    const int t = threadIdx.x;
    const int bid = blockIdx.x;
    if (bid < 192) {
        const int c = bid / 48, rem = bid % 48, ib = rem / 16, tile = rem % 16;
        const int n0 = (tile / 4) * 64, k0 = (tile % 4) * 64;
        const float* src = Wres + (size_t)(c * 3 + ib) * 65536;
        for (int i = 0; i < 16; i++) {
            int idx = t + 256 * i, r = idx >> 6, cc = idx & 63;
            sm[r * 65 + cc] = src[(size_t)(k0 + r) * 256 + n0 + cc];
        }
        __syncthreads();
        uint16_t* dst = Wrt + (size_t)(c * 3 + ib) * 65536;
        for (int i = 0; i < 16; i++) {
            int idx = t + 256 * i, rn = idx >> 6, ck = idx & 63;
            dst[(size_t)(n0 + rn) * 256 + k0 + ck] = (uint16_t)f2bf(sm[ck * 65 + rn]);
        }
    } else {
        const int c = bid - 192;
        for (int i = 0; i < 32; i++) {
            int idx = t + 256 * i, k = idx >> 8, n = idx & 255;
            sm[k * 257 + n] = W0[(size_t)c * 8192 + idx];
        }
        __syncthreads();
        for (int i = 0; i < 32; i++) {
            int idx = t + 256 * i, n = idx >> 5, k = idx & 31;
            W0t[(size_t)c * 8192 + idx] = (uint16_t)f2bf(sm[k * 257 + n]);
        }
    }
}

// ---------------- encode kernel: one level per block, level -> XCD pinned ----------------
// ROOFLINE (R3-R11): bound by L2 request rate (~295 G req/s vs ~307 G ceiling); 40 req/pt-lvl
// is the algorithmic floor (3-way mask specialization). Grid covers all NCHUNK=2049 chunks
// including the class-padding overflow chunk. Do not touch.
__global__ __launch_bounds__(256, 4) void k_encode(
    const float* __restrict__ xp, const uint32_t* __restrict__ T,
    uint32_t* __restrict__ encP)
{
    __shared__ float xs[256 * 6];
    const int t = threadIdx.x;
    const int NC8 = NCHUNK * 8;
    const int pass = (blockIdx.x >= NC8) ? 1 : 0;
    const int rem  = blockIdx.x - pass * NC8;
    const int l    = (rem & 7) + (pass << 3);
    const int chunk = rem >> 3;
    const int pbase = chunk << 8;

    for (int idx = t; idx < 256 * 6; idx += 256) {
        float v = xp[(size_t)pbase * 6 + idx];
        xs[idx] = fminf(fmaxf(v, 0.f), 1.f);
    }
    __syncthreads();

    const float res  = RESF[l];
    const float grid = GRIDF[l];
    float wv[6]; uint32_t ua[6], ub[6];
    #pragma unroll
    for (int d = 0; d < 6; d++) {
        float xv  = xs[t * 6 + d];
        float blf = floorf(xv * res);
        float w   = (xv - blf * grid) / (grid + 1e-6f);
        wv[d] = fminf(fmaxf(w, 0.f), 1.f);
        uint32_t uu = (uint32_t)(int)blf * PRS[d];
        ua[d] = uu; ub[d] = uu + PRS[d];
    }
    uint32_t HK[4]; float WK[4];
    #pragma unroll
    for (int q = 0; q < 4; q++) {
        const int b1 = (q >> 1) & 1, bb = q & 1;
        HK[q] = (b1 ? ub[4] : ua[4]) ^ (bb ? ub[5] : ua[5]);
        WK[q] = (bb ? wv[0] : 1.f - wv[0]) * (b1 ? wv[1] : 1.f - wv[1]);
    }
    uint32_t S8[8]; float W8[8];
    #pragma unroll
    for (int jj = 0; jj < 8; jj++) {
        const int j1 = jj >> 2, j = jj & 3;
        const int b1 = (j >> 1) & 1, bb = j & 1;
        const uint32_t hj = (b1 ? ub[2] : ua[2]) ^ (bb ? ub[3] : ua[3]);
        const float  wj = ((bb ? wv[2] : 1.f - wv[2]) * (b1 ? wv[3] : 1.f - wv[3]));
        S8[jj] = (j1 ? ub[1] : ua[1]) ^ hj;
        W8[jj] = (j1 ? wv[4] : 1.f - wv[4]) * wj;
    }
    const float w5a = 1.f - wv[5], w5b = wv[5];   // dim0 beta weights
    const uint32_t bl0  = ua[0];                  // prime = 1
    const uint32_t mask = bl0 ^ (bl0 + 1u);       // XOR delta of the dim0 vertex pair
    const uint32_t* __restrict__ Tl  = T + (size_t)l * HTABLE;
    const uint4*    __restrict__ Tl4 = reinterpret_cast<const uint4*>(Tl);

    float f0 = 0.f, f1 = 0.f;
    #pragma unroll 2
    for (int jj = 0; jj < 8; jj++) {
        const uint32_t Sj = S8[jj];
        const float   wj = W8[jj];
        #pragma unroll
        for (int k = 0; k < 4; k++) {
            const uint32_t h  = (bl0 ^ Sj ^ HK[k]) & TMASK;
            const float wS = wj * WK[k];
            uint32_t pa, pb;
            if (mask == 1u) {
                const uint2 pr = *(const uint2*)(Tl + (h & ~1u));
                pa = (h & 1u) ? pr.y : pr.x;
                pb = (h & 1u) ? pr.x : pr.y;
            } else if (mask == 3u) {
                const uint4 La = Tl4[h >> 2];
                const uint32_t i0 = h & 3u;
                pa = sel4(La, i0);
                pb = sel4(La, i0 ^ 3u);
            } else {
                pa = Tl[h];
                pb = Tl[h ^ mask];
            }
            const float e0x = __uint_as_float(pa << 16),  e0y = __uint_as_float(pa & 0xFFFF0000u);
            const float e1x = __uint_as_float(pb << 16),  e1y = __uint_as_float(pb & 0xFFFF0000u);
            f0 = fmaf(wS, fmaf(w5a, e0x, w5b * e1x), f0);
            f1 = fmaf(wS, fmaf(w5a, e0y, w5b * e1y), f1);
        }
    }
    const uint32_t val = f2bf(f0) | (f2bf(f1) << 16);
    __builtin_nontemporal_store(val, &encP[(size_t)l * BPAD + pbase + t]);
}

// ---------------- MFMA MLP — ping-pong hB, single barrier per residual layer ----------------
// R11 post-mortem: pk_bf16 null; 6 consecutive null/negative micro-opts. mlp2 is latency/
// barrier-bound (all pipes <50%, 124 regs/wave -> 4 waves/SIMD structural). LAST untried
// lever: the per-layer write-after-read barrier. Layer ib now READS hB[ib&1] and WRITES
// hB[(ib&1)^1] -> the post-ks barrier is unnecessary; one barrier per layer (was two).
// Also un-locksteps waves: one wave's VALU epilogue overlaps others' MFMA ks-loops (m114
// cross-wave pipe overlap). Safety: bs staging for layer ib sits after the previous
// trailing barrier (its readers done); hWr was last read two layers back, barrier between.
// LDS 73984 B (2x33792 hB + 5120 smU + 1024 bs + 256 permL) -> still 2 blocks/CU (was
// already reg-capped at 2). gfx950 allows >64KB workgroup LDS (HK 8-phase uses 128KB).
__global__ __launch_bounds__(512, 2) void k_mlp2(
    const int* __restrict__ lid, const uint32_t* __restrict__ encP,
    const uint16_t* __restrict__ W0t, const float* __restrict__ b0,
    const uint16_t* __restrict__ Wrt, const float* __restrict__ bres,
    const float* __restrict__ scales, const float* __restrict__ Wout, const float* __restrict__ bout,
    const int* __restrict__ perm, float* __restrict__ out)
{
    __shared__ uint16_t hB[2][64 * KSTR];     // 2 x 33792 B  H ping-pong, [buf][point][k] bf16
    __shared__ __align__(16) char smU[64 * KE * 2];  // 5120 B: encB (layer 0) UNION outP (output)
    __shared__ float    bs[256];              //  1024 B
    __shared__ int      permL[TILE];          //   256 B
    uint16_t* encB = (uint16_t*)smU;
    float*    outP = (float*)smU;

    const int t  = threadIdx.x;
    const int lane = t & 63;
    const int wv = t >> 6;          // wave id 0..7: 32-neuron slice
    const int mi = lane & 15;
    const int q  = lane >> 4;

    if (t < TILE) permL[t] = perm[(size_t)blockIdx.x * TILE + t];
    __syncthreads();
    const int g0 = permL[0];
    if (g0 < 0) return;
    const int c = lid[g0] & 3;

    // stage enc [point][k=2l..2l+1] and b0 — coalesced, nontemporal (read-once)
    if (t < 256) bs[t] = b0[c * 256 + t];
    for (int idx = t; idx < 16 * 64; idx += 512) {
        const int l = idx >> 6, pp = idx & 63;
        ((uint32_t*)encB)[pp * (KE / 2) + l] =
            __builtin_nontemporal_load(&encP[(size_t)l * BPAD + (size_t)blockIdx.x * TILE + pp]);
    }
    __syncthreads();

    floatx4 acc[2][4];
    floatx4 h_reg[2][4];

    // ---- layer 0: D = W0^T(256x32) . enc(32x64); wave wv covers neurons [wv*32, wv*32+32)
    {
        #pragma unroll
        for (int mt = 0; mt < 2; mt++)
            #pragma unroll
            for (int nt = 0; nt < 4; nt++) acc[mt][nt] = (floatx4){0.f, 0.f, 0.f, 0.f};
        const short8* Wp = (const short8*)(W0t + (size_t)c * 8192);
        short8 A[2], Bf[4];
        #pragma unroll
        for (int mt = 0; mt < 2; mt++) A[mt] = Wp[(wv * 32 + mt * 16 + mi) * 4 + q];
        #pragma unroll
        for (int nt = 0; nt < 4; nt++) Bf[nt] = *(const short8*)&encB[(nt * 16 + mi) * KE + q * 8];
        #pragma unroll
        for (int mt = 0; mt < 2; mt++)
            #pragma unroll
            for (int nt = 0; nt < 4; nt++)
                acc[mt][nt] = __builtin_amdgcn_mfma_f32_16x16x32_bf16(A[mt], Bf[nt], acc[mt][nt], 0, 0, 0);
        #pragma unroll
        for (int mt = 0; mt < 2; mt++) {
            const int nb = wv * 32 + mt * 16 + q * 4;
            #pragma unroll
            for (int nt = 0; nt < 4; nt++) {
                floatx4 u = acc[mt][nt], h;
                h[0] = relu_(u[0] + bs[nb + 0]); h[1] = relu_(u[1] + bs[nb + 1]);
                h[2] = relu_(u[2] + bs[nb + 2]); h[3] = relu_(u[3] + bs[nb + 3]);
                h_reg[mt][nt] = h;
                uint2 pk; pk.x = pk_bf16(h[0], h[1]); pk.y = pk_bf16(h[2], h[3]);
                *(uint2*)&hB[0][(nt * 16 + mi) * KSTR + nb] = pk;
            }
        }
    }
    __syncthreads();   // hB[0] visible; bs(b0) readers done

    // ---- 3 scaled residual blocks: read hB[ib&1], write hB[(ib&1)^1]; ONE barrier/layer
    #pragma unroll 1
    for (int ib = 0; ib < 3; ib++) {
        const uint16_t* hRd = hB[ib & 1];
        uint16_t*       hWr = hB[(ib & 1) ^ 1];
        if (t < 256) bs[t] = bres[(size_t)((c * 3 + ib) << 8) + t];   // after trailing barrier of prev layer
        const float s = scales[c * 3 + ib];
        #pragma unroll
        for (int mt = 0; mt < 2; mt++)
            #pragma unroll
            for (int nt = 0; nt < 4; nt++) acc[mt][nt] = (floatx4){0.f, 0.f, 0.f, 0.f};

        const short8* Wp = (const short8*)(Wrt + (size_t)(c * 3 + ib) * 65536);
        short8 Acur[2], Anext[2], Bf[4];
        #pragma unroll
        for (int mt = 0; mt < 2; mt++) Acur[mt] = Wp[(wv * 32 + mt * 16 + mi) * 32 + q];
        #pragma unroll 1
        for (int ks = 0; ks < 8; ks++) {
            #pragma unroll
            for (int nt = 0; nt < 4; nt++)
                Bf[nt] = *(const short8*)&hRd[(nt * 16 + mi) * KSTR + ks * 32 + q * 8];
            if (ks < 7) {
                #pragma unroll
                for (int mt = 0; mt < 2; mt++)
                    Anext[mt] = Wp[(wv * 32 + mt * 16 + mi) * 32 + (ks + 1) * 4 + q];
            }
            #pragma unroll
            for (int mt = 0; mt < 2; mt++)
                #pragma unroll
                for (int nt = 0; nt < 4; nt++)
                    acc[mt][nt] = __builtin_amdgcn_mfma_f32_16x16x32_bf16(Acur[mt], Bf[nt], acc[mt][nt], 0, 0, 0);
            #pragma unroll
            for (int mt = 0; mt < 2; mt++) Acur[mt] = Anext[mt];
        }
        // NO barrier here: epilogue writes the OTHER buffer (and each wave reads only its
        // own bs slice, staged before this layer's barrier window)
        #pragma unroll
        for (int mt = 0; mt < 2; mt++) {
            const int nb = wv * 32 + mt * 16 + q * 4;
            #pragma unroll
            for (int nt = 0; nt < 4; nt++) {
                floatx4 u = acc[mt][nt];
                floatx4 h = h_reg[mt][nt];
                h[0] = fmaf(s, relu_(u[0] + bs[nb + 0]), h[0]);
                h[1] = fmaf(s, relu_(u[1] + bs[nb + 1]), h[1]);
                h[2] = fmaf(s, relu_(u[2] + bs[nb + 2]), h[2]);
                h[3] = fmaf(s, relu_(u[3] + bs[nb + 3]), h[3]);
                h_reg[mt][nt] = h;
                if (ib < 2) {
                    uint2 pk; pk.x = pk_bf16(h[0], h[1]); pk.y = pk_bf16(h[2], h[3]);
                    *(uint2*)&hWr[(nt * 16 + mi) * KSTR + nb] = pk;
                }
            }
        }
        __syncthreads();   // single barrier: hWr visible, all hRd reads retired, bs readers done
    }

    // ---- output layer: out[p] = sum_n h[n][p] * Wout[n] + bout
    if (t < 256) bs[t] = Wout[c * 256 + t];   // after ib=2's trailing barrier
    __syncthreads();
    float po[4] = {0.f, 0.f, 0.f, 0.f};
    #pragma unroll
    for (int mt = 0; mt < 2; mt++) {
        const int nb = wv * 32 + mt * 16 + q * 4;
        const float w0v = bs[nb + 0], w1v = bs[nb + 1], w2v = bs[nb + 2], w3v = bs[nb + 3];
        #pragma unroll
        for (int nt = 0; nt < 4; nt++) {
            const floatx4 h = h_reg[mt][nt];
            po[nt] += h[0] * w0v + h[1] * w1v + h[2] * w2v + h[3] * w3v;
        }
    }
    #pragma unroll
    for (int nt = 0; nt < 4; nt++) {
        float v = po[nt];
        v += __shfl_xor(v, 16, 64);
        v += __shfl_xor(v, 32, 64);
        if (q == 0) outP[wv * 64 + nt * 16 + mi] = v;
    }
    __syncthreads();
    if (t < TILE) {
        float r = outP[t]       + outP[64 + t]  + outP[128 + t] + outP[192 + t]
                + outP[256 + t] + outP[320 + t] + outP[384 + t] + outP[448 + t] + bout[c];
        const int gi = permL[t];
        if (gi >= 0) out[gi] = r;
    }
}

extern "C" void kernel_launch(void* const* d_in, const int* in_sizes, int n_in,
                              void* d_out, int out_size, void* d_ws, size_t ws_size,
                              hipStream_t stream) {
    const float* x      = (const float*)d_in[0];
    const int*   lid    = (const int*)  d_in[1];
    const float* emb    = (const float*)d_in[2];
    const float* W0     = (const float*)d_in[3];
    const float* b0     = (const float*)d_in[4];
    const float* Wres   = (const float*)d_in[5];
    const float* bres   = (const float*)d_in[6];
    const float* scales = (const float*)d_in[7];
    const float* Wout   = (const float*)d_in[8];
    const float* bout   = (const float*)d_in[9];
    float* out = (float*)d_out;

    const int B = in_sizes[1];                          // 524288 points
    // workspace layout (~82.6 MB):
    int* cnt    = (int*)d_ws;                                        // [0,16)
    int* cursor = cnt + 4;                                           // [16,32)
    int*      perm = (int*)((char*)d_ws + 16384);                    // 2.0 MB padded permutation
    uint16_t* W0t  = (uint16_t*)((char*)d_ws + 2228224);             // 64 KB
    uint16_t* Wrt  = (uint16_t*)((char*)d_ws + 2359296);             // 1.5 MB
    uint32_t* encP = (uint32_t*)((char*)d_ws + (4ull  << 20));       // 4MB..37.6MB  [16][BPAD] bf16 pairs
    uint32_t* T    = (uint32_t*)((char*)d_ws + (38ull << 20));       // 38..70MB     bf16 pair table
    float*    xp   = (float*)   ((char*)d_ws + (70ull << 20));       // 70..82.6MB   permuted coords

    (void)hipMemsetAsync(d_ws, 0, 64, stream);
    (void)hipMemsetAsync(perm, 0xFF, (size_t)NTILE * TILE * sizeof(int), stream);
    k_packtab<<<(16 * (int)HTABLE) / 256, 256, 0, stream>>>(emb, T);
    k_prep   <<<196, 256, 0, stream>>>(Wres, W0, Wrt, W0t);
    k_count  <<<B / 256, 256, 0, stream>>>(lid, B, cnt);
    k_offsets<<<1, 64, 0, stream>>>(cnt, cursor);
    k_scatter<<<B / 256, 256, 0, stream>>>(lid, x, B, cursor, perm, xp);
    k_encode <<<NCHUNK * 16, 256, 0, stream>>>(xp, T, encP);
    k_mlp2   <<<NTILE, 512, 0, stream>>>(lid, encP, W0t, b0, Wrt, bres, scales, Wout, bout, perm, out);
}